// Round 9
// baseline (54.745 us; speedup 1.0000x reference)
//
#include <hip/hip_runtime.h>

typedef __bf16 v8bf __attribute__((ext_vector_type(8)));
typedef float f32x4 __attribute__((ext_vector_type(4)));
typedef unsigned int u32;
typedef unsigned int u32x4 __attribute__((ext_vector_type(4)));

#define C_IN 256
#define HW   64
#define OHW  63
#define NOC  128

// Wf: [kp(4)][khkw(4)][cblk(32)][oc(128)][j(8)] bf16, 1 MiB. Coalesced.
__global__ void wprep(const float* __restrict__ w, __bf16* __restrict__ Wf) {
  int f = blockIdx.x;                 // 512 filters
  int c = threadIdx.x;                // 256 channels
  f32x4 v = *(const f32x4*)(w + (size_t)f * 1024 + c * 4);  // 4 khkw taps
  int oc = f >> 2, kp = f & 3;
#pragma unroll
  for (int khkw = 0; khkw < 4; ++khkw)
    Wf[(((size_t)(kp * 4 + khkw) * 32 + (c >> 3)) * 128 + oc) * 8 + (c & 7)] =
        (__bf16)v[khkw];
}

// xprep: x (NCHW f32) -> x' [n][q(8)][y(64)][wp(32)][par(2)][c(32)] bf16
// (plain/unswizzled content; swizzle is applied via src-permute in main).
// One wave per (n,q,y): coalesced f32x4 reads, b128 writes (L2-combined).
__global__ __launch_bounds__(256) void xprep(const float* __restrict__ x,
                                             __bf16* __restrict__ xp) {
  int u = blockIdx.x * 4 + (threadIdx.x >> 6);   // 8192 units
  int lane = threadIdx.x & 63;
  int y = u & 63, q = (u >> 6) & 7, n = u >> 9;
  int w4 = lane & 15;                 // w-quad index
  int co = lane >> 4;                 // c-octet 0..3
  const float* src =
      x + (((size_t)(n * 256 + q * 32 + co * 8) * 64 + y) * 64) + w4 * 4;
  f32x4 xv[8];
#pragma unroll
  for (int j = 0; j < 8; ++j) xv[j] = *(const f32x4*)(src + (size_t)j * 4096);
  char* dst = (char*)xp + (((size_t)(n * 8 + q) * 64 + y) * 4096) + co * 16;
#pragma unroll
  for (int ww = 0; ww < 4; ++ww) {
    int w_ = w4 * 4 + ww;
    u32x4 pk;
#pragma unroll
    for (int k = 0; k < 4; ++k) {
      u32 lo = (u32)__builtin_bit_cast(unsigned short, (__bf16)xv[2 * k][ww]);
      u32 hi = (u32)__builtin_bit_cast(unsigned short, (__bf16)xv[2 * k + 1][ww]);
      pk[k] = lo | (hi << 16);
    }
    *(u32x4*)(dst + (w_ >> 1) * 128 + (w_ & 1) * 64) = pk;
  }
}

__device__ __forceinline__ void gl_lds16(const void* g, void* l) {
  __builtin_amdgcn_global_load_lds(
      (const __attribute__((address_space(1))) u32*)g,
      (__attribute__((address_space(3))) u32*)l, 16, 0, 0);
}

// Main: block = n x 4 out rows x 128 oc, 1024 thr (16 waves, 4/SIMD).
// wave = ocg(4: 32 oc) x kp(4). LDS [dy(5)][wp(32)][par(2)][c(32)] bf16 per
// chunk (20 KB), dbuf, content XOR-swizzled via permuted global src (m173):
// LDS row wp holds plain sub ^ ((wp&7)<<4). Staging = 20 global_load_lds
// dwordx4 per chunk: zero VGPR, zero VALU repack, zero ds_writes.
__global__ __launch_bounds__(1024, 4) void robin_main(
    const __bf16* __restrict__ xp, const __bf16* __restrict__ Wf,
    const float* __restrict__ bias, float* __restrict__ out) {
  __shared__ __align__(16) char xs[2][20480];

  const int tid  = threadIdx.x;
  const int lane = tid & 63;
  const int wid  = tid >> 6;
  const int hb   = blockIdx.x;       // 16
  const int n    = blockIdx.y;       // 16
  const int h0   = hb * 4;

  const int ocg  = wid >> 2;         // 0..3 -> 32 oc each
  const int kp   = wid & 3;          // parity class
  const int ph   = kp >> 1, pw = kp & 1;
  const int lcol = lane & 15;        // pixel col (B) / oc row (A)
  const int lg   = lane >> 4;        // k-octet group

  // lane-constant src sub-offset within each 1KB segment (inverse swizzle):
  // LDS slot (l>>3 row, (l&7)*16 sub) <- plain sub ^ ((l>>3)<<4)
  const int lsub = ((lane >> 3) * 128) + (((lane & 7) * 16) ^ ((lane >> 3) << 4));

  // B-frag offsets, swizzled-read side: boff2[khkw][hh], r -> +8192.
  // wcol==64 (only lcol=15,hh=1,pw=kw=1 -> discarded output) clamped to 63.
  int boff2[4][2];
#pragma unroll
  for (int khkw = 0; khkw < 4; ++khkw) {
    int kh = khkw >> 1, kw = khkw & 1;
    int dy0 = ph + kh;
#pragma unroll
    for (int hh = 0; hh < 2; ++hh) {
      int wcol = 2 * (hh * 16 + lcol) + pw + kw;
      if (wcol > 63) wcol = 63;
      int wp = wcol >> 1;
      boff2[khkw][hh] = dy0 * 4096 +
          ((wp * 128 + (wcol & 1) * 64 + lg * 16) ^ ((wp & 7) << 4));
    }
  }

  f32x4 acc[2][4];
#pragma unroll
  for (int m = 0; m < 2; ++m)
#pragma unroll
    for (int f = 0; f < 4; ++f) acc[m][f] = (f32x4){0.f, 0.f, 0.f, 0.f};

  v8bf a_reg[4][2];
  const char* xpc = (const char*)xp;

#define A_LOAD(QQ)                                                             \
  {                                                                            \
    _Pragma("unroll") for (int khkw = 0; khkw < 4; ++khkw) {                   \
      const __bf16* wp_ =                                                      \
          Wf + (((size_t)(kp * 4 + khkw) * 32 + (QQ) * 4 + lg) * 128 +        \
                ocg * 32 + lcol) * 8;                                          \
      a_reg[khkw][0] = *(const v8bf*)wp_;                                      \
      a_reg[khkw][1] = *(const v8bf*)(wp_ + 128);                              \
    }                                                                          \
  }

  // 20 gl_lds instrs per chunk: wave wid -> (dy=wid>>2, wq=wid&3); waves 0..3
  // also issue the dy=4 row. LDS dest linear; src pre-permuted via lsub.
#define ISSUE(QQ)                                                              \
  {                                                                            \
    char* db = xs[(QQ) & 1];                                                   \
    const char* sb = xpc + (((size_t)n * 8 + (QQ)) * 64) * 4096;               \
    {                                                                          \
      int dy = wid >> 2, wq = wid & 3;                                         \
      int y = h0 + dy;               /* h0<=60, dy<=3 -> y<=63 */              \
      gl_lds16(sb + (size_t)y * 4096 + wq * 1024 + lsub,                       \
               db + dy * 4096 + wq * 1024);                                    \
    }                                                                          \
    if (wid < 4) {                                                             \
      int y = h0 + 4; if (y > 63) y = 63;                                      \
      gl_lds16(sb + (size_t)y * 4096 + wid * 1024 + lsub,                      \
               db + 4 * 4096 + wid * 1024);                                    \
    }                                                                          \
  }

#define COMPUTE(QQ)                                                            \
  {                                                                            \
    const char* xsb = xs[(QQ) & 1];                                            \
    _Pragma("unroll") for (int khkw = 0; khkw < 4; ++khkw) {                   \
      v8bf b[4];                                                               \
      _Pragma("unroll") for (int r = 0; r < 2; ++r)                            \
        _Pragma("unroll") for (int hh = 0; hh < 2; ++hh)                       \
          b[r * 2 + hh] =                                                      \
              *(const v8bf*)(xsb + boff2[khkw][hh] + r * 8192);                \
      _Pragma("unroll") for (int m = 0; m < 2; ++m)                            \
        _Pragma("unroll") for (int f = 0; f < 4; ++f)                          \
          acc[m][f] = __builtin_amdgcn_mfma_f32_16x16x32_bf16(                 \
              a_reg[khkw][m], b[f], acc[m][f], 0, 0, 0);                       \
    }                                                                          \
  }

  // prologue: stage chunk 0 (syncthreads drains vmcnt)
  ISSUE(0);
  __syncthreads();

  for (int q = 0; q < 8; ++q) {
    A_LOAD(q);                // issued FIRST: compute's vmcnt wait leaves the
    if (q < 7) ISSUE(q + 1);  // next chunk's gl_lds in flight (FIFO)
    COMPUTE(q);
    if (q < 7) __syncthreads();  // drain vmcnt (loads q+1 done) + barrier
  }

  // ---- epilogue: D col=lane&15 (pixel), row=(lane>>4)*4+reg (oc) ----
#pragma unroll
  for (int m = 0; m < 2; ++m) {
#pragma unroll
    for (int r = 0; r < 2; ++r) {
      const int h = h0 + 2 * r + ph;
#pragma unroll
      for (int hh = 0; hh < 2; ++hh) {
        const int w = 2 * (hh * 16 + lcol) + pw;
        f32x4 v = acc[m][r * 2 + hh];
        if (h < OHW && w < OHW) {
#pragma unroll
          for (int reg = 0; reg < 4; ++reg) {
            int oc = ocg * 32 + m * 16 + lg * 4 + reg;
            out[((size_t)(n * NOC + oc) * OHW + h) * OHW + w] =
                v[reg] + bias[oc * 4 + kp];
          }
        }
      }
    }
  }
#undef A_LOAD
#undef ISSUE
#undef COMPUTE
}

extern "C" void kernel_launch(void* const* d_in, const int* in_sizes, int n_in,
                              void* d_out, int out_size, void* d_ws, size_t ws_size,
                              hipStream_t stream) {
  const float* x      = (const float*)d_in[0];
  const float* weight = (const float*)d_in[1];
  const float* bias   = (const float*)d_in[2];
  float* out          = (float*)d_out;
  __bf16* Wf = (__bf16*)d_ws;                          // 1 MiB
  __bf16* xp = (__bf16*)((char*)d_ws + (1 << 20));     // 33.5 MiB transposed x

  wprep<<<512, 256, 0, stream>>>(weight, Wf);
  xprep<<<2048, 256, 0, stream>>>(x, xp);
  robin_main<<<dim3(16, 16), 1024, 0, stream>>>(xp, Wf, bias, out);
}

// Round 10
// 53.775 us; speedup vs baseline: 1.0180x; 1.0180x over previous
//
#include <hip/hip_runtime.h>

typedef __bf16 v8bf __attribute__((ext_vector_type(8)));
typedef float f32x4 __attribute__((ext_vector_type(4)));
typedef unsigned int u32;
typedef unsigned int u32x4 __attribute__((ext_vector_type(4)));

#define C_IN 256
#define HW   64
#define OHW  63
#define NOC  128

// Wf: [kp(4)][khkw(4)][cblk(32)][oc(128)][j(8)] bf16, 1 MiB. Coalesced.
__global__ void wprep(const float* __restrict__ w, __bf16* __restrict__ Wf) {
  int f = blockIdx.x;                 // 512 filters
  int c = threadIdx.x;                // 256 channels
  f32x4 v = *(const f32x4*)(w + (size_t)f * 1024 + c * 4);  // 4 khkw taps
  int oc = f >> 2, kp = f & 3;
#pragma unroll
  for (int khkw = 0; khkw < 4; ++khkw)
    Wf[(((size_t)(kp * 4 + khkw) * 32 + (c >> 3)) * 128 + oc) * 8 + (c & 7)] =
        (__bf16)v[khkw];
}

// xprep: x (NCHW f32) -> x' [n][q(8)][y(64)][wp(32)][par(2)][c(32)] bf16
// (plain/unswizzled content; swizzle is applied via src-permute in main).
__global__ __launch_bounds__(256) void xprep(const float* __restrict__ x,
                                             __bf16* __restrict__ xp) {
  int u = blockIdx.x * 4 + (threadIdx.x >> 6);   // 8192 units
  int lane = threadIdx.x & 63;
  int y = u & 63, q = (u >> 6) & 7, n = u >> 9;
  int w4 = lane & 15;                 // w-quad index
  int co = lane >> 4;                 // c-octet 0..3
  const float* src =
      x + (((size_t)(n * 256 + q * 32 + co * 8) * 64 + y) * 64) + w4 * 4;
  f32x4 xv[8];
#pragma unroll
  for (int j = 0; j < 8; ++j) xv[j] = *(const f32x4*)(src + (size_t)j * 4096);
  char* dst = (char*)xp + (((size_t)(n * 8 + q) * 64 + y) * 4096) + co * 16;
#pragma unroll
  for (int ww = 0; ww < 4; ++ww) {
    int w_ = w4 * 4 + ww;
    u32x4 pk;
#pragma unroll
    for (int k = 0; k < 4; ++k) {
      u32 lo = (u32)__builtin_bit_cast(unsigned short, (__bf16)xv[2 * k][ww]);
      u32 hi = (u32)__builtin_bit_cast(unsigned short, (__bf16)xv[2 * k + 1][ww]);
      pk[k] = lo | (hi << 16);
    }
    *(u32x4*)(dst + (w_ >> 1) * 128 + (w_ & 1) * 64) = pk;
  }
}

__device__ __forceinline__ void gl_lds16(const void* g, void* l) {
  __builtin_amdgcn_global_load_lds(
      (const __attribute__((address_space(1))) u32*)g,
      (__attribute__((address_space(3))) u32*)l, 16, 0, 0);
}

// Main: 512 thr (8 waves), grid (16 hb, 16 n, 2 ocz) = 512 blocks = 2/CU.
// Per-wave shape identical to R9: wave = ocg x kp, 32 oc x (2 rows x 32 w).
// ocg = ocz*2 + (wid>>2). LDS [dy(5)][wp(32)][par(2)][c(32)] bf16 (20 KB),
// dbuf, content swizzled via permuted global src. Sibling block on the same
// CU is barrier-independent -> overlaps this block's vmcnt drain + epilogue.
__global__ __launch_bounds__(512, 4) void robin_main(
    const __bf16* __restrict__ xp, const __bf16* __restrict__ Wf,
    const float* __restrict__ bias, float* __restrict__ out) {
  __shared__ __align__(16) char xs[2][20480];

  const int tid  = threadIdx.x;
  const int lane = tid & 63;
  const int wid  = tid >> 6;         // 0..7
  const int hb   = blockIdx.x;       // 16
  const int n    = blockIdx.y;       // 16
  const int h0   = hb * 4;

  const int ocg  = (blockIdx.z << 1) | (wid >> 2);   // 0..3 -> 32 oc each
  const int kp   = wid & 3;          // parity class
  const int ph   = kp >> 1, pw = kp & 1;
  const int lcol = lane & 15;        // pixel col (B) / oc row (A)
  const int lg   = lane >> 4;        // k-octet group

  // lane-constant src sub-offset within each 1KB segment (inverse swizzle):
  // LDS slot (l>>3 row, (l&7)*16 sub) <- plain sub ^ ((l>>3)<<4)
  const int lsub = ((lane >> 3) * 128) + (((lane & 7) * 16) ^ ((lane >> 3) << 4));

  // B-frag offsets, swizzled-read side: boff2[khkw][hh], r -> +8192.
  // wcol==64 (only lcol=15,hh=1,pw=kw=1 -> discarded output) clamped to 63.
  int boff2[4][2];
#pragma unroll
  for (int khkw = 0; khkw < 4; ++khkw) {
    int kh = khkw >> 1, kw = khkw & 1;
    int dy0 = ph + kh;
#pragma unroll
    for (int hh = 0; hh < 2; ++hh) {
      int wcol = 2 * (hh * 16 + lcol) + pw + kw;
      if (wcol > 63) wcol = 63;
      int wp = wcol >> 1;
      boff2[khkw][hh] = dy0 * 4096 +
          ((wp * 128 + (wcol & 1) * 64 + lg * 16) ^ ((wp & 7) << 4));
    }
  }

  f32x4 acc[2][4];
#pragma unroll
  for (int m = 0; m < 2; ++m)
#pragma unroll
    for (int f = 0; f < 4; ++f) acc[m][f] = (f32x4){0.f, 0.f, 0.f, 0.f};

  v8bf a_reg[4][2];
  const char* xpc = (const char*)xp;

#define A_LOAD(QQ)                                                             \
  {                                                                            \
    _Pragma("unroll") for (int khkw = 0; khkw < 4; ++khkw) {                   \
      const __bf16* wp_ =                                                      \
          Wf + (((size_t)(kp * 4 + khkw) * 32 + (QQ) * 4 + lg) * 128 +        \
                ocg * 32 + lcol) * 8;                                          \
      a_reg[khkw][0] = *(const v8bf*)wp_;                                      \
      a_reg[khkw][1] = *(const v8bf*)(wp_ + 128);                              \
    }                                                                          \
  }

  // 20 x 1KB segments per chunk (seg = dy*4 + wq): wave wid issues seg wid,
  // seg wid+8; waves 0..3 also seg wid+16. LDS dest wave-uniform + linear;
  // global src per-lane pre-permuted (lsub) -> swizzled content.
#define ISSUE(QQ)                                                              \
  {                                                                            \
    char* db = xs[(QQ) & 1];                                                   \
    const char* sb = xpc + (((size_t)n * 8 + (QQ)) * 64) * 4096;               \
    {                                                                          \
      int seg = wid, dy = seg >> 2, wq = seg & 3;                              \
      int y = h0 + dy;                                                         \
      gl_lds16(sb + (size_t)y * 4096 + wq * 1024 + lsub, db + seg * 1024);     \
    }                                                                          \
    {                                                                          \
      int seg = wid + 8, dy = seg >> 2, wq = seg & 3;                          \
      int y = h0 + dy;                                                         \
      gl_lds16(sb + (size_t)y * 4096 + wq * 1024 + lsub, db + seg * 1024);     \
    }                                                                          \
    if (wid < 4) {                                                             \
      int y = h0 + 4; if (y > 63) y = 63;                                      \
      gl_lds16(sb + (size_t)y * 4096 + wid * 1024 + lsub,                      \
               db + (16 + wid) * 1024);                                        \
    }                                                                          \
  }

#define COMPUTE(QQ)                                                            \
  {                                                                            \
    const char* xsb = xs[(QQ) & 1];                                            \
    _Pragma("unroll") for (int khkw = 0; khkw < 4; ++khkw) {                   \
      v8bf b[4];                                                               \
      _Pragma("unroll") for (int r = 0; r < 2; ++r)                            \
        _Pragma("unroll") for (int hh = 0; hh < 2; ++hh)                       \
          b[r * 2 + hh] =                                                      \
              *(const v8bf*)(xsb + boff2[khkw][hh] + r * 8192);                \
      _Pragma("unroll") for (int m = 0; m < 2; ++m)                            \
        _Pragma("unroll") for (int f = 0; f < 4; ++f)                          \
          acc[m][f] = __builtin_amdgcn_mfma_f32_16x16x32_bf16(                 \
              a_reg[khkw][m], b[f], acc[m][f], 0, 0, 0);                       \
    }                                                                          \
  }

  // prologue: stage chunk 0 (syncthreads drains vmcnt)
  ISSUE(0);
  __syncthreads();

  for (int q = 0; q < 8; ++q) {
    A_LOAD(q);                // issued FIRST: compute's vmcnt wait leaves the
    if (q < 7) ISSUE(q + 1);  // next chunk's gl_lds in flight (FIFO)
    COMPUTE(q);
    if (q < 7) __syncthreads();  // drain vmcnt (loads q+1 done) + barrier
  }

  // ---- epilogue: D col=lane&15 (pixel), row=(lane>>4)*4+reg (oc) ----
#pragma unroll
  for (int m = 0; m < 2; ++m) {
#pragma unroll
    for (int r = 0; r < 2; ++r) {
      const int h = h0 + 2 * r + ph;
#pragma unroll
      for (int hh = 0; hh < 2; ++hh) {
        const int w = 2 * (hh * 16 + lcol) + pw;
        f32x4 v = acc[m][r * 2 + hh];
        if (h < OHW && w < OHW) {
#pragma unroll
          for (int reg = 0; reg < 4; ++reg) {
            int oc = ocg * 32 + m * 16 + lg * 4 + reg;
            out[((size_t)(n * NOC + oc) * OHW + h) * OHW + w] =
                v[reg] + bias[oc * 4 + kp];
          }
        }
      }
    }
  }
#undef A_LOAD
#undef ISSUE
#undef COMPUTE
}

extern "C" void kernel_launch(void* const* d_in, const int* in_sizes, int n_in,
                              void* d_out, int out_size, void* d_ws, size_t ws_size,
                              hipStream_t stream) {
  const float* x      = (const float*)d_in[0];
  const float* weight = (const float*)d_in[1];
  const float* bias   = (const float*)d_in[2];
  float* out          = (float*)d_out;
  __bf16* Wf = (__bf16*)d_ws;                          // 1 MiB
  __bf16* xp = (__bf16*)((char*)d_ws + (1 << 20));     // 33.5 MiB transposed x

  wprep<<<512, 256, 0, stream>>>(weight, Wf);
  xprep<<<2048, 256, 0, stream>>>(x, xp);
  robin_main<<<dim3(16, 16, 2), 512, 0, stream>>>(xp, Wf, bias, out);
}